// Round 2
// baseline (214.297 us; speedup 1.0000x reference)
//
#include <hip/hip_runtime.h>
#include <hip/hip_bf16.h>
#include <stdint.h>

// Problem constants
#define B_   2
#define H_   16
#define N_   2048
#define D_   1024
#define DH   64
#define MTOK 4096   // B_*N_

typedef __attribute__((ext_vector_type(8)))  short bf16x8;
typedef __attribute__((ext_vector_type(4)))  float f32x4;
typedef __attribute__((ext_vector_type(16))) float f32x16;
typedef __attribute__((ext_vector_type(2)))  unsigned u32x2;
typedef __attribute__((ext_vector_type(4)))  unsigned short us4;

static __device__ __forceinline__ unsigned short f2bf(float f) {
    union { float f; unsigned u; } v; v.f = f;
    unsigned r = v.u + 0x7fffu + ((v.u >> 16) & 1u);
    return (unsigned short)(r >> 16);
}

static __device__ __forceinline__ unsigned cvt_pk_bf16(float lo, float hi) {
    unsigned r;
    asm("v_cvt_pk_bf16_f32 %0, %1, %2" : "=v"(r) : "v"(lo), "v"(hi));
    return r;
}

static __device__ __forceinline__ bf16x8 frag_from_u32(unsigned a, unsigned b, unsigned c, unsigned d) {
    union { unsigned u[4]; bf16x8 v; } x;
    x.u[0] = a; x.u[1] = b; x.u[2] = c; x.u[3] = d;
    return x.v;
}

static __device__ __forceinline__ void load_lds16(const void* g, void* l) {
    __builtin_amdgcn_global_load_lds(
        (const __attribute__((address_space(1))) unsigned int*)g,
        (__attribute__((address_space(3))) unsigned int*)l, 16, 0, 0);
}

// ---------------- fp32 -> bf16 elementwise (x) ----------------
__global__ __launch_bounds__(256) void k_cvt_x(const float* __restrict__ x,
                                               unsigned short* __restrict__ xb, int n) {
    int idx = (blockIdx.x * 256 + threadIdx.x) * 4;
    if (idx < n) {
        float4 v = *(const float4*)(x + idx);
        us4 o;
        o.x = f2bf(v.x); o.y = f2bf(v.y); o.z = f2bf(v.z); o.w = f2bf(v.w);
        *(us4*)(xb + idx) = o;
    }
}

// ------------- fp32 [R][C] -> bf16 [C][R] (weights) -------------
__global__ __launch_bounds__(256) void k_transpose_w(const float* __restrict__ in,
                                                     unsigned short* __restrict__ out,
                                                     int R, int C) {
    __shared__ float tile[64][65];
    int c0 = blockIdx.x * 64, r0 = blockIdx.y * 64;
    int t = threadIdx.x;
    int tr = t >> 4, tc = (t & 15) * 4;
#pragma unroll
    for (int p = 0; p < 4; p++) {
        int row = p * 16 + tr;
        float4 v = *(const float4*)(in + (size_t)(r0 + row) * C + c0 + tc);
        tile[row][tc + 0] = v.x; tile[row][tc + 1] = v.y;
        tile[row][tc + 2] = v.z; tile[row][tc + 3] = v.w;
    }
    __syncthreads();
    int oc = t >> 4, orr = (t & 15) * 4;
#pragma unroll
    for (int p = 0; p < 4; p++) {
        int crow = p * 16 + oc;   // original column == output row
        us4 o;
        o.x = f2bf(tile[orr + 0][crow]);
        o.y = f2bf(tile[orr + 1][crow]);
        o.z = f2bf(tile[orr + 2][crow]);
        o.w = f2bf(tile[orr + 3][crow]);
        *(us4*)(out + (size_t)(c0 + crow) * R + r0 + orr) = o;
    }
}

// ---------- bf16 [BH][N][DH] -> [BH][DH][N]  (V transpose) ----------
__global__ __launch_bounds__(256) void k_transpose_v(const unsigned short* __restrict__ v,
                                                     unsigned short* __restrict__ vt) {
    __shared__ unsigned short tile[64][72];
    int bh = blockIdx.y;
    int n0 = blockIdx.x * 64;
    const unsigned short* src = v + (size_t)bh * N_ * DH + (size_t)n0 * DH;
    unsigned short* dst = vt + (size_t)bh * DH * N_ + n0;
    int t = threadIdx.x;
#pragma unroll
    for (int p = 0; p < 2; p++) {
        int id = p * 256 + t;
        int row = id >> 3, c8 = (id & 7) * 8;
        bf16x8 val = *(const bf16x8*)(src + row * DH + c8);
#pragma unroll
        for (int j = 0; j < 8; j++) tile[row][c8 + j] = (unsigned short)val[j];
    }
    __syncthreads();
#pragma unroll
    for (int p = 0; p < 2; p++) {
        int id = p * 256 + t;
        int drow = id >> 3, n8 = (id & 7) * 8;
        bf16x8 ov;
#pragma unroll
        for (int j = 0; j < 8; j++) ov[j] = (short)tile[n8 + j][drow];
        *(bf16x8*)(dst + (size_t)drow * N_ + n8) = ov;
    }
}

// ---------------- m97-style 128x128 GEMM, BK=64 ----------------
// MODE 0: A = xb [4096][1024], Bt = w1t [3072][1024]; epilogue: +b1,
//         q scaled by 0.125, scatter into qkvh [3][B][H][N][DH] bf16.
// MODE 1: A = attn [B*H][N][DH] (head-strided k), Bt = w2t [1024][1024];
//         epilogue: +b2 -> fp32 out [4096][1024].
template <int MODE>
__global__ __launch_bounds__(256) void k_gemm(const unsigned short* __restrict__ A,
                                              const unsigned short* __restrict__ Bt,
                                              const float* __restrict__ bias,
                                              unsigned short* __restrict__ qkv,
                                              float* __restrict__ outp) {
    __shared__ unsigned short As[128 * 64];
    __shared__ unsigned short Bs[128 * 64];
    const int K = 1024;
    int tid = threadIdx.x;
    int lane = tid & 63, wv = tid >> 6;
    int wm = wv >> 1, wn = wv & 1;
    int m0 = blockIdx.y * 128;
    int n0 = blockIdx.x * 128;
    int bIdx = m0 >> 11;       // batch index (MODE 1)
    int ntok0 = m0 & 2047;

    f32x4 acc[4][4];
#pragma unroll
    for (int i = 0; i < 4; i++)
#pragma unroll
        for (int j = 0; j < 4; j++) {
            f32x4 z; z[0] = 0.f; z[1] = 0.f; z[2] = 0.f; z[3] = 0.f;
            acc[i][j] = z;
        }

#pragma unroll 1
    for (int k0 = 0; k0 < K; k0 += 64) {
        const unsigned short* aptr;
        int arst;
        if (MODE == 0) { aptr = A + (size_t)m0 * K + k0; arst = K; }
        else {
            int hh = k0 >> 6;
            aptr = A + ((size_t)(bIdx * H_ + hh) * N_ + ntok0) * DH;
            arst = DH;
        }
        const unsigned short* bptr = Bt + (size_t)n0 * K + k0;
#pragma unroll
        for (int i = 0; i < 4; i++) {
            int cidb = i * 256 + wv * 64;          // wave-uniform chunk base
            int cid = cidb + lane;
            load_lds16(aptr + (size_t)(cid >> 3) * arst + (cid & 7) * 8, &As[cidb * 8]);
            load_lds16(bptr + (size_t)(cid >> 3) * K + (cid & 7) * 8, &Bs[cidb * 8]);
        }
        __syncthreads();
#pragma unroll
        for (int kk = 0; kk < 2; ++kk) {
            bf16x8 af[4], bfr[4];
            int ko = kk * 32 + (lane >> 4) * 8;
#pragma unroll
            for (int mi = 0; mi < 4; mi++)
                af[mi] = *(const bf16x8*)&As[(wm * 64 + mi * 16 + (lane & 15)) * 64 + ko];
#pragma unroll
            for (int ni = 0; ni < 4; ni++)
                bfr[ni] = *(const bf16x8*)&Bs[(wn * 64 + ni * 16 + (lane & 15)) * 64 + ko];
#pragma unroll
            for (int mi = 0; mi < 4; mi++)
#pragma unroll
                for (int ni = 0; ni < 4; ni++)
                    acc[mi][ni] = __builtin_amdgcn_mfma_f32_16x16x32_bf16(
                        af[mi], bfr[ni], acc[mi][ni], 0, 0, 0);
        }
        __syncthreads();
    }

    // epilogue  (C/D: col = lane&15, row = (lane>>4)*4 + r)
#pragma unroll
    for (int ni = 0; ni < 4; ni++) {
        int col = n0 + wn * 64 + ni * 16 + (lane & 15);
        float bv = bias[col];
        if (MODE == 0) {
            int which = col >> 10;
            int hd = (col >> 6) & 15;
            int dh = col & 63;
            float scl = (which == 0) ? 0.125f : 1.0f;   // fold softmax scale into Q
#pragma unroll
            for (int mi = 0; mi < 4; mi++) {
                int rbase = m0 + wm * 64 + mi * 16 + (lane >> 4) * 4;
#pragma unroll
                for (int r = 0; r < 4; r++) {
                    int tok = rbase + r;
                    int bb = tok >> 11, nn = tok & 2047;
                    float vvv = (acc[mi][ni][r] + bv) * scl;
                    qkv[((size_t)((which * B_ + bb) * H_ + hd) * N_ + nn) * DH + dh] = f2bf(vvv);
                }
            }
        } else {
#pragma unroll
            for (int mi = 0; mi < 4; mi++) {
                int rbase = m0 + wm * 64 + mi * 16 + (lane >> 4) * 4;
#pragma unroll
                for (int r = 0; r < 4; r++)
                    outp[(size_t)(rbase + r) * D_ + col] = acc[mi][ni][r] + bv;
            }
        }
    }
}

// ---------------- flash attention, swapped QK^T, no LDS ----------------
// qh: [3][B][H][N][DH] bf16 (q pre-scaled by 0.125); vt: [B*H][DH][N] bf16
// o:  [B*H][N][DH] bf16
__global__ __launch_bounds__(256) void k_attn(const unsigned short* __restrict__ qh,
                                              const unsigned short* __restrict__ vt,
                                              unsigned short* __restrict__ o) {
    int tid = threadIdx.x;
    int lane = tid & 63, wv = tid >> 6;
    int bh = blockIdx.x >> 4;
    int qt = blockIdx.x & 15;
    int q0 = qt * 128 + wv * 32;
    const size_t bhQK = (size_t)bh * N_ * DH;
    const unsigned short* qp = qh + bhQK;
    const unsigned short* kp = qh + (size_t)B_ * H_ * N_ * DH + bhQK;
    const unsigned short* vp = vt + (size_t)bh * DH * N_;
    int ln = lane & 31, hi = lane >> 5;

    // Q fragments (B operand of mfma(K,Q)): lane owns q-row = ln
    bf16x8 qf[4];
#pragma unroll
    for (int kk = 0; kk < 4; kk++)
        qf[kk] = *(const bf16x8*)(qp + (size_t)(q0 + ln) * DH + kk * 16 + hi * 8);

    f32x16 o0, o1;
#pragma unroll
    for (int r = 0; r < 16; r++) { o0[r] = 0.f; o1[r] = 0.f; }
    float m = -INFINITY, l = 0.f;

#pragma unroll 1
    for (int kv0 = 0; kv0 < N_; kv0 += 32) {
        // K fragments (A operand): row = kv = ln, k = kk*16 + hi*8
        bf16x8 kf[4];
#pragma unroll
        for (int kk = 0; kk < 4; kk++)
            kf[kk] = *(const bf16x8*)(kp + (size_t)(kv0 + ln) * DH + kk * 16 + hi * 8);
        // V^T fragments for PV (A operand): row = d, k = kv
        const unsigned short* vbase = vp + (size_t)ln * N_ + kv0 + hi * 8;
        bf16x8 v00 = *(const bf16x8*)(vbase);
        bf16x8 v01 = *(const bf16x8*)(vbase + 16);
        bf16x8 v10 = *(const bf16x8*)(vbase + (size_t)32 * N_);
        bf16x8 v11 = *(const bf16x8*)(vbase + (size_t)32 * N_ + 16);

        f32x16 s;
#pragma unroll
        for (int r = 0; r < 16; r++) s[r] = 0.f;
#pragma unroll
        for (int kk = 0; kk < 4; kk++)
            s = __builtin_amdgcn_mfma_f32_32x32x16_bf16(kf[kk], qf[kk], s, 0, 0, 0);
        // s[r] = S^T[kv][q]: q = ln, kv = (r&3) + 8*(r>>2) + 4*hi

        // online softmax (per-lane q-row; partner lane = lane^32 holds other 16 kv)
        float mt = s[0];
#pragma unroll
        for (int r = 1; r < 16; r++) mt = fmaxf(mt, s[r]);
        mt = fmaxf(mt, __shfl_xor(mt, 32));
        float mn = fmaxf(m, mt);
        float fs = __expf(m - mn);
        float p[16], sum = 0.f;
#pragma unroll
        for (int r = 0; r < 16; r++) { p[r] = __expf(s[r] - mn); sum += p[r]; }
        sum += __shfl_xor(sum, 32);
        l = l * fs + sum;
        m = mn;
#pragma unroll
        for (int r = 0; r < 16; r++) { o0[r] *= fs; o1[r] *= fs; }

        // pack P -> bf16 pairs. Lane (ln,hi) holds kv = (r&3)+8*(r>>2)+4*hi:
        //   pk[0]=(4hi,4hi+1) pk[1]=(4hi+2,4hi+3) pk[2]=(8+4hi,..) pk[3]=(10+4hi,..)
        //   pk[4..7]: same +16.
        unsigned pk[8];
#pragma unroll
        for (int i = 0; i < 8; i++) pk[i] = cvt_pk_bf16(p[2 * i], p[2 * i + 1]);
        // permlane32_swap(vdst,vsrc): new_vdst = {lo: vdst_lo, hi: vsrc_lo},
        //                             new_vsrc = {lo: vdst_hi, hi: vsrc_hi}.
        // B-operand needs word w of lane(ln,hi) = kv pair (hi*8 + 2w, +1):
        //   w0={pk0_h0|pk2_h0} w1={pk1_h0|pk3_h0} w2={pk0_h1|pk2_h1} w3={pk1_h1|pk3_h1}
        u32x2 s0 = __builtin_amdgcn_permlane32_swap(pk[0], pk[2], false, false);
        u32x2 s1 = __builtin_amdgcn_permlane32_swap(pk[1], pk[3], false, false);
        u32x2 s2 = __builtin_amdgcn_permlane32_swap(pk[4], pk[6], false, false);
        u32x2 s3 = __builtin_amdgcn_permlane32_swap(pk[5], pk[7], false, false);
        bf16x8 pf0 = frag_from_u32(s0[0], s1[0], s0[1], s1[1]);  // kv 0..15
        bf16x8 pf1 = frag_from_u32(s2[0], s3[0], s2[1], s3[1]);  // kv 16..31

        // O^T[d][q] += V^T[d][kv] * P^T[kv][q]
        o0 = __builtin_amdgcn_mfma_f32_32x32x16_bf16(v00, pf0, o0, 0, 0, 0);
        o0 = __builtin_amdgcn_mfma_f32_32x32x16_bf16(v01, pf1, o0, 0, 0, 0);
        o1 = __builtin_amdgcn_mfma_f32_32x32x16_bf16(v10, pf0, o1, 0, 0, 0);
        o1 = __builtin_amdgcn_mfma_f32_32x32x16_bf16(v11, pf1, o1, 0, 0, 0);
    }

    float inv = 1.0f / l;
    unsigned short* ob = o + bhQK + (size_t)(q0 + ln) * DH;
#pragma unroll
    for (int t = 0; t < 2; t++) {
#pragma unroll
        for (int g = 0; g < 4; g++) {
            int d = t * 32 + g * 8 + hi * 4;   // rows: (r&3)+8*(r>>2)+4*hi
            float a0 = (t ? o1[g * 4 + 0] : o0[g * 4 + 0]) * inv;
            float a1 = (t ? o1[g * 4 + 1] : o0[g * 4 + 1]) * inv;
            float a2 = (t ? o1[g * 4 + 2] : o0[g * 4 + 2]) * inv;
            float a3 = (t ? o1[g * 4 + 3] : o0[g * 4 + 3]) * inv;
            us4 w;
            w.x = f2bf(a0); w.y = f2bf(a1); w.z = f2bf(a2); w.w = f2bf(a3);
            *(us4*)(ob + d) = w;
        }
    }
}

extern "C" void kernel_launch(void* const* d_in, const int* in_sizes, int n_in,
                              void* d_out, int out_size, void* d_ws, size_t ws_size,
                              hipStream_t stream) {
    const float* x  = (const float*)d_in[0];
    const float* W1 = (const float*)d_in[1];
    const float* b1 = (const float*)d_in[2];
    const float* W2 = (const float*)d_in[3];
    const float* b2 = (const float*)d_in[4];
    float* out = (float*)d_out;

    char* ws = (char*)d_ws;
    unsigned short* xb   = (unsigned short*)(ws);                  //  8,388,608 B
    unsigned short* w1t  = (unsigned short*)(ws + 8388608);        //  6,291,456 B
    unsigned short* w2t  = (unsigned short*)(ws + 14680064);       //  2,097,152 B
    unsigned short* qkvh = (unsigned short*)(ws + 16777216);       // 25,165,824 B
    unsigned short* vth  = (unsigned short*)(ws + 41943040);       //  8,388,608 B
    unsigned short* attn = (unsigned short*)(ws + 50331648);       //  8,388,608 B
    // total 58,720,256 B of d_ws used

    k_cvt_x<<<4096, 256, 0, stream>>>(x, xb, MTOK * D_);
    k_transpose_w<<<dim3(48, 16), 256, 0, stream>>>(W1, w1t, D_, 3 * D_);
    k_transpose_w<<<dim3(16, 16), 256, 0, stream>>>(W2, w2t, D_, D_);
    k_gemm<0><<<dim3(24, 32), 256, 0, stream>>>(xb, w1t, b1, qkvh, nullptr);
    k_transpose_v<<<dim3(32, 32), 256, 0, stream>>>(qkvh + (size_t)2 * B_ * H_ * N_ * DH, vth);
    k_attn<<<512, 256, 0, stream>>>(qkvh, vth, attn);
    k_gemm<1><<<dim3(8, 32), 256, 0, stream>>>(attn, w2t, b2, nullptr, out);
}